// Round 2
// baseline (445.638 us; speedup 1.0000x reference)
//
#include <hip/hip_runtime.h>
#include <hip/hip_bf16.h>

typedef _Float16 half8 __attribute__((ext_vector_type(8)));
typedef _Float16 half2_t __attribute__((ext_vector_type(2)));
typedef float f32x4 __attribute__((ext_vector_type(4)));

#define B_SZ 64
#define T_SZ 512
#define E_SZ 768
#define H_SZ 256
#define V_SZ 3072

// workspace layout (bytes)
#define WS_X     0u          // _Float16 x[T][B][H]           16,777,216 B
#define WS_WT    16777216u   // _Float16 Wt[256][768] (Wxh^T)    393,216 B
#define WS_WF    17170432u   // (unused; kept so WS_H offset is stable)
#define WS_H     17301504u   // float    h[64][256]               65,536 B

// fast tanh: 1 - 2/(1+exp(2x)); exact at +/-inf, ~1e-6 rel err
static __device__ __forceinline__ float fast_tanh(float x) {
  float e = __builtin_amdgcn_exp2f(x * 2.8853900817779268f); // exp(2x)
  return 1.0f - 2.0f * __builtin_amdgcn_rcpf(1.0f + e);
}

// v_dot2_f32_f16: c += h2.x*w2.x + h2.y*w2.y  (f32 accumulate, f16 inputs)
static __device__ __forceinline__ float dot2(unsigned int h2, unsigned int w2, float c) {
  return __builtin_amdgcn_fdot2(__builtin_bit_cast(half2_t, h2),
                                __builtin_bit_cast(half2_t, w2), c, false);
}

// ---------------- k0: prep f16 Wt layout for k1 (small) ----------------
__global__ __launch_bounds__(256) void k0_convert(
    const float* __restrict__ Wxh,
    _Float16* __restrict__ Wt)
{
  int gid = blockIdx.x * 256 + threadIdx.x;           // 768 WGs = 196608
  if (gid < E_SZ * H_SZ) {
    int e = gid >> 8, h = gid & 255;
    Wt[h * E_SZ + e] = (_Float16)Wxh[gid];
  }
}

// ---------------- k1: x[t,b,:] = emb[idx[b,t],:] @ Wxh  (MFMA f16) ----------------
__global__ __launch_bounds__(256) void k1_xproj(
    const int* __restrict__ idx,
    const float* __restrict__ emb,
    const _Float16* __restrict__ Wt,
    _Float16* __restrict__ x)
{
  const int tid  = threadIdx.x;
  const int w    = tid >> 6;
  const int lane = tid & 63;
  const int m16  = lane & 15;
  const int quad = lane >> 4;
  const int r = blockIdx.x * 64 + w * 16 + m16;     // row in [T*B], r = t*64 + b
  const int t = r >> 6;
  const int b = r & 63;
  const int erow = idx[b * T_SZ + t];
  const float* Arow = emb + (size_t)erow * E_SZ + quad * 8;   // A[m][k=quad*8+j]

  __shared__ __align__(16) _Float16 bp[2][16 * 64 * 8]; // 2 x 16KB fragment panels
  int n_[4], kb_[4];
#pragma unroll
  for (int pp = 0; pp < 4; ++pp) {
    int f = tid + 256 * pp;
    n_[pp]  = ((f >> 6) << 4) | (f & 15);
    kb_[pp] = (f >> 4) & 3;
  }
  uint4 stg[4];
#pragma unroll
  for (int pp = 0; pp < 4; ++pp)
    stg[pp] = *(const uint4*)(Wt + (size_t)n_[pp] * E_SZ + kb_[pp] * 8);
  f32x4 af0 = *(const f32x4*)(Arow);
  f32x4 af1 = *(const f32x4*)(Arow + 4);

  f32x4 acc[16];
#pragma unroll
  for (int n = 0; n < 16; ++n) { f32x4 z = {0.f, 0.f, 0.f, 0.f}; acc[n] = z; }

  // stage panel 0
#pragma unroll
  for (int pp = 0; pp < 4; ++pp)
    *(uint4*)(bp[0] + (size_t)(tid + 256 * pp) * 8) = stg[pp];
  __syncthreads();

#pragma unroll 1
  for (int ki = 0; ki < 24; ++ki) {
    const _Float16* cur = bp[ki & 1];
    f32x4 af0n = af0, af1n = af1;
    if (ki < 23) {                            // prefetch next panel + next A
#pragma unroll
      for (int pp = 0; pp < 4; ++pp)
        stg[pp] = *(const uint4*)(Wt + (size_t)n_[pp] * E_SZ + (ki + 1) * 32 + kb_[pp] * 8);
      af0n = *(const f32x4*)(Arow + (ki + 1) * 32);
      af1n = *(const f32x4*)(Arow + (ki + 1) * 32 + 4);
    }
    half8 a;
#pragma unroll
    for (int e = 0; e < 4; ++e) { a[e] = (_Float16)af0[e]; a[4 + e] = (_Float16)af1[e]; }
#pragma unroll
    for (int nt = 0; nt < 16; ++nt) {
      half8 bb = *(const half8*)(cur + (size_t)(nt * 64 + lane) * 8);
      acc[nt] = __builtin_amdgcn_mfma_f32_16x16x32_f16(a, bb, acc[nt], 0, 0, 0);
    }
    if (ki < 23) {                            // write next buffer, one barrier
#pragma unroll
      for (int pp = 0; pp < 4; ++pp)
        *(uint4*)(bp[(ki + 1) & 1] + (size_t)(tid + 256 * pp) * 8) = stg[pp];
      __syncthreads();
    }
    af0 = af0n; af1 = af1n;
  }
  const int rbase = blockIdx.x * 64 + w * 16 + quad * 4;  // C/D: col=lane&15, row=quad*4+reg
#pragma unroll
  for (int nt = 0; nt < 16; ++nt) {
    const int col = nt * 16 + m16;
#pragma unroll
    for (int rg = 0; rg < 4; ++rg) {
      x[(size_t)(rbase + rg) * H_SZ + col] = (_Float16)acc[nt][rg];
    }
  }
}

// ---------------- k2: VALU-dot2 recurrence, pressure-bounded ----------------
// R1 regression diagnosis: VGPR_Count=92 => wc[128] was NOT in arch VGPRs.
// The fully-unrolled kk loop let the scheduler hoist all 32 uint4 LDS loads
// (128 VGPRs live) on top of wc => pressure >256 => wc spilled, ~128 copy-back
// moves + waits per step (1354 cyc/step observed vs ~600 predicted).
// Fix: 16-deep explicit rotation (p0..p15, static indices, reload right after
// first use) bounds live hq regs to 64; launch_bounds(256,2) caps the unified
// budget at 256 so the scheduler cannot re-create the spill. Peak pressure
// ~= 128(wc) + 64(p) + ~30 misc < 256. Accumulation order identical to R1.
static __device__ __forceinline__ float rnn_step(
    const _Float16* __restrict__ hr, const unsigned int* __restrict__ wc, float xf)
{
  const uint4* hq4 = (const uint4*)hr;
  uint4 p0 = hq4[0],  p1 = hq4[1],  p2 = hq4[2],  p3 = hq4[3],
        p4 = hq4[4],  p5 = hq4[5],  p6 = hq4[6],  p7 = hq4[7],
        p8 = hq4[8],  p9 = hq4[9],  p10 = hq4[10], p11 = hq4[11],
        p12 = hq4[12], p13 = hq4[13], p14 = hq4[14], p15 = hq4[15];
  float a0 = 0.f, a1 = 0.f, a2 = 0.f, a3 = 0.f;
#define DOT4(P, KB) \
  a0 = dot2(P.x, wc[4 * (KB) + 0], a0); \
  a1 = dot2(P.y, wc[4 * (KB) + 1], a1); \
  a2 = dot2(P.z, wc[4 * (KB) + 2], a2); \
  a3 = dot2(P.w, wc[4 * (KB) + 3], a3);
  DOT4(p0, 0)   p0  = hq4[16];
  DOT4(p1, 1)   p1  = hq4[17];
  DOT4(p2, 2)   p2  = hq4[18];
  DOT4(p3, 3)   p3  = hq4[19];
  DOT4(p4, 4)   p4  = hq4[20];
  DOT4(p5, 5)   p5  = hq4[21];
  DOT4(p6, 6)   p6  = hq4[22];
  DOT4(p7, 7)   p7  = hq4[23];
  DOT4(p8, 8)   p8  = hq4[24];
  DOT4(p9, 9)   p9  = hq4[25];
  DOT4(p10, 10) p10 = hq4[26];
  DOT4(p11, 11) p11 = hq4[27];
  DOT4(p12, 12) p12 = hq4[28];
  DOT4(p13, 13) p13 = hq4[29];
  DOT4(p14, 14) p14 = hq4[30];
  DOT4(p15, 15) p15 = hq4[31];
  DOT4(p0, 16)  DOT4(p1, 17)  DOT4(p2, 18)  DOT4(p3, 19)
  DOT4(p4, 20)  DOT4(p5, 21)  DOT4(p6, 22)  DOT4(p7, 23)
  DOT4(p8, 24)  DOT4(p9, 25)  DOT4(p10, 26) DOT4(p11, 27)
  DOT4(p12, 28) DOT4(p13, 29) DOT4(p14, 30) DOT4(p15, 31)
#undef DOT4
  float y = (a0 + a1) + (a2 + a3);
  return fast_tanh(y + xf);
}

__global__ __launch_bounds__(256, 2) void k2_rnn(
    const float* __restrict__ Whh,
    const _Float16* __restrict__ x,
    const float* __restrict__ Bh,
    float* __restrict__ hout,
    float* __restrict__ hidout)
{
  const int b   = blockIdx.x;
  const int tid = threadIdx.x;
  __shared__ __align__(16) _Float16 hb[2][H_SZ];   // h as f16, double-buffered

  // W column tid, packed f16 pairs: wc[p] = (Whh[2p][tid], Whh[2p+1][tid])
  unsigned int wc[128];
#pragma unroll
  for (int p = 0; p < 128; ++p) {
    _Float16 w0 = (_Float16)Whh[(size_t)(2 * p)     * H_SZ + tid];
    _Float16 w1 = (_Float16)Whh[(size_t)(2 * p + 1) * H_SZ + tid];
    half2_t pk; pk[0] = w0; pk[1] = w1;
    wc[p] = __builtin_bit_cast(unsigned int, pk);
  }

  const float bhj = Bh[tid];
  const _Float16* xp = x + b * H_SZ + tid;
  _Float16 xA = xp[0];                               // for t=0
  _Float16 xB = xp[(size_t)(B_SZ * H_SZ)];           // for t=1
  hb[1][tid] = (_Float16)0.f;                        // t=0 reads buffer 1 = zeros
  float hval = 0.f;
  __syncthreads();

#pragma unroll 1
  for (int tt = 0; tt < 256; ++tt) {
    // ---- step A: t = 2tt, read hb[1], write hb[0]
    float xfA = (float)xA + bhj;        // waits on load issued 2 steps ago
    int ta = 2 * tt + 2; ta = ta > 511 ? 511 : ta;
    xA = xp[(size_t)ta * (B_SZ * H_SZ)];   // reload same reg: next wait 2 steps out
    hval = rnn_step(hb[1], wc, xfA);
    hb[0][tid] = (_Float16)hval;
    __syncthreads();
    // ---- step B: t = 2tt+1, read hb[0], write hb[1]
    float xfB = (float)xB + bhj;
    int tb = 2 * tt + 3; tb = tb > 511 ? 511 : tb;
    xB = xp[(size_t)tb * (B_SZ * H_SZ)];
    hval = rnn_step(hb[0], wc, xfB);
    hb[1][tid] = (_Float16)hval;
    __syncthreads();
  }
  hout[b * H_SZ + tid] = hval;
  hidout[b * H_SZ + tid] = hval;
}

// ---------------- k3: out = hidden @ Wy + By  (all f32) ----------------
__global__ __launch_bounds__(256) void k3_out(
    const float* __restrict__ h,
    const float* __restrict__ Wy,
    const float* __restrict__ By,
    float* __restrict__ out)
{
  __shared__ float hs[H_SZ];
  const int c = blockIdx.x;   // vocab chunk
  const int b = blockIdx.y;   // batch
  const int v = c * 256 + threadIdx.x;
  hs[threadIdx.x] = h[b * H_SZ + threadIdx.x];
  __syncthreads();
  float acc = By[v];
#pragma unroll 8
  for (int jj = 0; jj < H_SZ; ++jj) {
    acc += hs[jj] * Wy[(size_t)jj * V_SZ + v];
  }
  out[(size_t)b * V_SZ + v] = acc;
}

extern "C" void kernel_launch(void* const* d_in, const int* in_sizes, int n_in,
                              void* d_out, int out_size, void* d_ws, size_t ws_size,
                              hipStream_t stream)
{
  const int*   idx = (const int*)d_in[0];
  const float* emb = (const float*)d_in[1];
  const float* Wxh = (const float*)d_in[2];
  const float* Whh = (const float*)d_in[3];
  const float* Wy  = (const float*)d_in[4];
  const float* By  = (const float*)d_in[5];
  const float* Bh  = (const float*)d_in[6];

  char* ws = (char*)d_ws;
  _Float16* x    = (_Float16*)(ws + WS_X);
  _Float16* Wt   = (_Float16*)(ws + WS_WT);
  float*    hbuf = (float*)(ws + WS_H);

  float* out    = (float*)d_out;
  float* hidout = out + (size_t)B_SZ * V_SZ;

  k0_convert<<<768, 256, 0, stream>>>(Wxh, Wt);
  k1_xproj  <<<512, 256, 0, stream>>>(idx, emb, Wt, x);
  k2_rnn    <<<64, 256, 0, stream>>>(Whh, x, Bh, hbuf, hidout);
  k3_out    <<<dim3(12, 64), 256, 0, stream>>>(hbuf, Wy, By, out);
}

// Round 3
// 443.681 us; speedup vs baseline: 1.0044x; 1.0044x over previous
//
#include <hip/hip_runtime.h>
#include <hip/hip_bf16.h>

typedef _Float16 half8 __attribute__((ext_vector_type(8)));
typedef _Float16 half2_t __attribute__((ext_vector_type(2)));
typedef float f32x4 __attribute__((ext_vector_type(4)));

#define B_SZ 64
#define T_SZ 512
#define E_SZ 768
#define H_SZ 256
#define V_SZ 3072

// workspace layout (bytes)
#define WS_X     0u          // _Float16 x[T][B][H]           16,777,216 B
#define WS_WT    16777216u   // _Float16 Wt[256][768] (Wxh^T)    393,216 B
#define WS_WQ    17170432u   // uint32 Wq[128][256] packed f16 pairs 131,072 B
#define WS_H     17301504u   // float    h[64][256]               65,536 B

// fast tanh: 1 - 2/(1+exp(2x)); exact at +/-inf, ~1e-6 rel err
static __device__ __forceinline__ float fast_tanh(float x) {
  float e = __builtin_amdgcn_exp2f(x * 2.8853900817779268f); // exp(2x)
  return 1.0f - 2.0f * __builtin_amdgcn_rcpf(1.0f + e);
}

// v_dot2_f32_f16: c += h2.x*w2.x + h2.y*w2.y  (f32 accumulate, f16 inputs)
static __device__ __forceinline__ float dot2(unsigned int h2, unsigned int w2, float c) {
  return __builtin_amdgcn_fdot2(__builtin_bit_cast(half2_t, h2),
                                __builtin_bit_cast(half2_t, w2), c, false);
}

// ---------------- k0: prep f16 layouts (small) ----------------
// Wt[h][e] = Wxh[e][h] (k1 B panels).
// Wq[p][c] = packed (f16(Whh[2p][c]), f16(Whh[2p+1][c]))  -- k2 weight dwords.
__global__ __launch_bounds__(256) void k0_convert(
    const float* __restrict__ Wxh,
    const float* __restrict__ Whh,
    _Float16* __restrict__ Wt,
    unsigned int* __restrict__ Wq)
{
  int gid = blockIdx.x * 256 + threadIdx.x;           // 768 WGs = 196608
  if (gid < E_SZ * H_SZ) {
    int e = gid >> 8, h = gid & 255;
    Wt[h * E_SZ + e] = (_Float16)Wxh[gid];
  }
  if (gid < 128 * H_SZ) {                             // 32768 pair-dwords
    int p = gid >> 8, c = gid & 255;
    half2_t pk;
    pk[0] = (_Float16)Whh[(size_t)(2 * p)     * H_SZ + c];
    pk[1] = (_Float16)Whh[(size_t)(2 * p + 1) * H_SZ + c];
    Wq[gid] = __builtin_bit_cast(unsigned int, pk);
  }
}

// ---------------- k1: x[t,b,:] = emb[idx[b,t],:] @ Wxh  (MFMA f16) ----------------
__global__ __launch_bounds__(256) void k1_xproj(
    const int* __restrict__ idx,
    const float* __restrict__ emb,
    const _Float16* __restrict__ Wt,
    _Float16* __restrict__ x)
{
  const int tid  = threadIdx.x;
  const int w    = tid >> 6;
  const int lane = tid & 63;
  const int m16  = lane & 15;
  const int quad = lane >> 4;
  const int r = blockIdx.x * 64 + w * 16 + m16;     // row in [T*B], r = t*64 + b
  const int t = r >> 6;
  const int b = r & 63;
  const int erow = idx[b * T_SZ + t];
  const float* Arow = emb + (size_t)erow * E_SZ + quad * 8;   // A[m][k=quad*8+j]

  __shared__ __align__(16) _Float16 bp[2][16 * 64 * 8]; // 2 x 16KB fragment panels
  int n_[4], kb_[4];
#pragma unroll
  for (int pp = 0; pp < 4; ++pp) {
    int f = tid + 256 * pp;
    n_[pp]  = ((f >> 6) << 4) | (f & 15);
    kb_[pp] = (f >> 4) & 3;
  }
  uint4 stg[4];
#pragma unroll
  for (int pp = 0; pp < 4; ++pp)
    stg[pp] = *(const uint4*)(Wt + (size_t)n_[pp] * E_SZ + kb_[pp] * 8);
  f32x4 af0 = *(const f32x4*)(Arow);
  f32x4 af1 = *(const f32x4*)(Arow + 4);

  f32x4 acc[16];
#pragma unroll
  for (int n = 0; n < 16; ++n) { f32x4 z = {0.f, 0.f, 0.f, 0.f}; acc[n] = z; }

  // stage panel 0
#pragma unroll
  for (int pp = 0; pp < 4; ++pp)
    *(uint4*)(bp[0] + (size_t)(tid + 256 * pp) * 8) = stg[pp];
  __syncthreads();

#pragma unroll 1
  for (int ki = 0; ki < 24; ++ki) {
    const _Float16* cur = bp[ki & 1];
    f32x4 af0n = af0, af1n = af1;
    if (ki < 23) {                            // prefetch next panel + next A
#pragma unroll
      for (int pp = 0; pp < 4; ++pp)
        stg[pp] = *(const uint4*)(Wt + (size_t)n_[pp] * E_SZ + (ki + 1) * 32 + kb_[pp] * 8);
      af0n = *(const f32x4*)(Arow + (ki + 1) * 32);
      af1n = *(const f32x4*)(Arow + (ki + 1) * 32 + 4);
    }
    half8 a;
#pragma unroll
    for (int e = 0; e < 4; ++e) { a[e] = (_Float16)af0[e]; a[4 + e] = (_Float16)af1[e]; }
#pragma unroll
    for (int nt = 0; nt < 16; ++nt) {
      half8 bb = *(const half8*)(cur + (size_t)(nt * 64 + lane) * 8);
      acc[nt] = __builtin_amdgcn_mfma_f32_16x16x32_f16(a, bb, acc[nt], 0, 0, 0);
    }
    if (ki < 23) {                            // write next buffer, one barrier
#pragma unroll
      for (int pp = 0; pp < 4; ++pp)
        *(uint4*)(bp[(ki + 1) & 1] + (size_t)(tid + 256 * pp) * 8) = stg[pp];
      __syncthreads();
    }
    af0 = af0n; af1 = af1n;
  }
  const int rbase = blockIdx.x * 64 + w * 16 + quad * 4;  // C/D: col=lane&15, row=quad*4+reg
#pragma unroll
  for (int nt = 0; nt < 16; ++nt) {
    const int col = nt * 16 + m16;
#pragma unroll
    for (int rg = 0; rg < 4; ++rg) {
      x[(size_t)(rbase + rg) * H_SZ + col] = (_Float16)acc[nt][rg];
    }
  }
}

// ---------------- k2: K-split VALU-dot2 recurrence ----------------
// R1/R2 post-mortem: compiler refuses to register-allocate wc[128] (VGPR=92
// both rounds regardless of budget) and backs it with AGPR-spill copies:
// ~590 issue cyc/step (256 dots + ~256 copies) + ~760 stall at 1 wave/SIMD.
// Fix: split K across 2x256 threads. Each thread holds wc[64] (same footprint
// as a normal GEMM acc block -> register-resident), computes a half-dot over
// K=128, halves combine via LDS part[]. 512 threads = 8 waves = 2/SIMD, so
// sibling waves cover each other's LDS/barrier stalls. Per-SIMD dot issue is
// unchanged (2 x 64 dots x 2cyc = 256 cyc = structural floor).
__global__ __launch_bounds__(512, 2) void k2_rnn(
    const unsigned int* __restrict__ Wq,
    const _Float16* __restrict__ x,
    const float* __restrict__ Bh,
    float* __restrict__ hout,
    float* __restrict__ hidout)
{
  const int b   = blockIdx.x;
  const int tid = threadIdx.x;        // 0..511
  const int g   = tid >> 8;           // K-half: g=0 -> rows 0..127, g=1 -> 128..255
  const int c   = tid & 255;          // output column
  __shared__ __align__(16) _Float16 hb[2][H_SZ];   // h as f16, double-buffered
  __shared__ float part[H_SZ];                     // g=1 partial sums

  // wc[i] = packed pair (Whh[2*(g*64+i)][c], Whh[2*(g*64+i)+1][c])
  unsigned int wc[64];
#pragma unroll
  for (int i = 0; i < 64; ++i)
    wc[i] = Wq[(size_t)(g * 64 + i) * H_SZ + c];

  const float bhj = Bh[c];
  const _Float16* xp = x + b * H_SZ + c;
  _Float16 xA = xp[0];                               // for t=0
  _Float16 xB = xp[(size_t)(B_SZ * H_SZ)];           // for t=1
  if (tid < H_SZ) hb[1][tid] = (_Float16)0.f;        // t=0 reads buffer 1 = zeros
  float hval = 0.f;
  __syncthreads();

#define K2_STEP(HR, HW, XREG)                                          \
  {                                                                    \
    const uint4* hq4 = ((const uint4*)(HR)) + g * 16;                  \
    float a0 = 0.f, a1 = 0.f, a2 = 0.f, a3 = 0.f;                      \
    _Pragma("unroll")                                                  \
    for (int kk = 0; kk < 16; ++kk) {                                  \
      uint4 hq = hq4[kk];                                              \
      a0 = dot2(hq.x, wc[4 * kk + 0], a0);                             \
      a1 = dot2(hq.y, wc[4 * kk + 1], a1);                             \
      a2 = dot2(hq.z, wc[4 * kk + 2], a2);                             \
      a3 = dot2(hq.w, wc[4 * kk + 3], a3);                             \
    }                                                                  \
    float psum = (a0 + a1) + (a2 + a3);                                \
    if (g) part[c] = psum;                                             \
    __syncthreads();                                                   \
    if (!g) {                                                          \
      float y = psum + part[c] + (float)(XREG) + bhj;                  \
      hval = fast_tanh(y);                                             \
      (HW)[c] = (_Float16)hval;                                        \
    }                                                                  \
    __syncthreads();                                                   \
  }

#pragma unroll 1
  for (int tt = 0; tt < 256; ++tt) {
    // ---- step A: t = 2tt, read hb[1], write hb[0]
    int ta = 2 * tt + 2; ta = ta > 511 ? 511 : ta;
    _Float16 xAc = xA;
    xA = xp[(size_t)ta * (B_SZ * H_SZ)];   // reload same reg: wait is 2 steps out
    K2_STEP(hb[1], hb[0], xAc)
    // ---- step B: t = 2tt+1, read hb[0], write hb[1]
    int tb = 2 * tt + 3; tb = tb > 511 ? 511 : tb;
    _Float16 xBc = xB;
    xB = xp[(size_t)tb * (B_SZ * H_SZ)];
    K2_STEP(hb[0], hb[1], xBc)
  }
#undef K2_STEP
  if (!g) {
    hout[b * H_SZ + c] = hval;
    hidout[b * H_SZ + c] = hval;
  }
}

// ---------------- k3: out = hidden @ Wy + By  (all f32) ----------------
__global__ __launch_bounds__(256) void k3_out(
    const float* __restrict__ h,
    const float* __restrict__ Wy,
    const float* __restrict__ By,
    float* __restrict__ out)
{
  __shared__ float hs[H_SZ];
  const int c = blockIdx.x;   // vocab chunk
  const int b = blockIdx.y;   // batch
  const int v = c * 256 + threadIdx.x;
  hs[threadIdx.x] = h[b * H_SZ + threadIdx.x];
  __syncthreads();
  float acc = By[v];
#pragma unroll 8
  for (int jj = 0; jj < H_SZ; ++jj) {
    acc += hs[jj] * Wy[(size_t)jj * V_SZ + v];
  }
  out[(size_t)b * V_SZ + v] = acc;
}

extern "C" void kernel_launch(void* const* d_in, const int* in_sizes, int n_in,
                              void* d_out, int out_size, void* d_ws, size_t ws_size,
                              hipStream_t stream)
{
  const int*   idx = (const int*)d_in[0];
  const float* emb = (const float*)d_in[1];
  const float* Wxh = (const float*)d_in[2];
  const float* Whh = (const float*)d_in[3];
  const float* Wy  = (const float*)d_in[4];
  const float* By  = (const float*)d_in[5];
  const float* Bh  = (const float*)d_in[6];

  char* ws = (char*)d_ws;
  _Float16*     x    = (_Float16*)(ws + WS_X);
  _Float16*     Wt   = (_Float16*)(ws + WS_WT);
  unsigned int* Wq   = (unsigned int*)(ws + WS_WQ);
  float*        hbuf = (float*)(ws + WS_H);

  float* out    = (float*)d_out;
  float* hidout = out + (size_t)B_SZ * V_SZ;

  k0_convert<<<768, 256, 0, stream>>>(Wxh, Whh, Wt, Wq);
  k1_xproj  <<<512, 256, 0, stream>>>(idx, emb, Wt, x);
  k2_rnn    <<<64, 512, 0, stream>>>(Wq, x, Bh, hbuf, hidout);
  k3_out    <<<dim3(12, 64), 256, 0, stream>>>(hbuf, Wy, By, out);
}

// Round 4
// 442.036 us; speedup vs baseline: 1.0081x; 1.0037x over previous
//
#include <hip/hip_runtime.h>
#include <hip/hip_bf16.h>

typedef _Float16 half8 __attribute__((ext_vector_type(8)));
typedef _Float16 half2_t __attribute__((ext_vector_type(2)));
typedef float f32x4 __attribute__((ext_vector_type(4)));

#define B_SZ 64
#define T_SZ 512
#define E_SZ 768
#define H_SZ 256
#define V_SZ 3072

// workspace layout (bytes)
#define WS_X     0u          // _Float16 x[T][B][H]           16,777,216 B
#define WS_WT    16777216u   // _Float16 Wt[256][768] (Wxh^T)    393,216 B
#define WS_WQ    17170432u   // uint32 Wq[128][256] packed f16 pairs 131,072 B
#define WS_H     17301504u   // float    h[64][256]               65,536 B

// fast tanh: 1 - 2/(1+exp(2x)); exact at +/-inf, ~1e-6 rel err
static __device__ __forceinline__ float fast_tanh(float x) {
  float e = __builtin_amdgcn_exp2f(x * 2.8853900817779268f); // exp(2x)
  return 1.0f - 2.0f * __builtin_amdgcn_rcpf(1.0f + e);
}

// v_dot2_f32_f16: c += h2.x*w2.x + h2.y*w2.y  (f32 accumulate, f16 inputs)
static __device__ __forceinline__ float dot2(unsigned int h2, unsigned int w2, float c) {
  return __builtin_amdgcn_fdot2(__builtin_bit_cast(half2_t, h2),
                                __builtin_bit_cast(half2_t, w2), c, false);
}

// ---------------- k0: prep f16 layouts (small) ----------------
// Wt[h][e] = Wxh[e][h] (k1 B panels).
// Wq[p][c] = packed (f16(Whh[2p][c]), f16(Whh[2p+1][c]))  -- k2 weight dwords.
__global__ __launch_bounds__(256) void k0_convert(
    const float* __restrict__ Wxh,
    const float* __restrict__ Whh,
    _Float16* __restrict__ Wt,
    unsigned int* __restrict__ Wq)
{
  int gid = blockIdx.x * 256 + threadIdx.x;           // 768 WGs = 196608
  if (gid < E_SZ * H_SZ) {
    int e = gid >> 8, h = gid & 255;
    Wt[h * E_SZ + e] = (_Float16)Wxh[gid];
  }
  if (gid < 128 * H_SZ) {                             // 32768 pair-dwords
    int p = gid >> 8, c = gid & 255;
    half2_t pk;
    pk[0] = (_Float16)Whh[(size_t)(2 * p)     * H_SZ + c];
    pk[1] = (_Float16)Whh[(size_t)(2 * p + 1) * H_SZ + c];
    Wq[gid] = __builtin_bit_cast(unsigned int, pk);
  }
}

// ---------------- k1: x[t,b,:] = emb[idx[b,t],:] @ Wxh  (MFMA f16) ----------------
__global__ __launch_bounds__(256) void k1_xproj(
    const int* __restrict__ idx,
    const float* __restrict__ emb,
    const _Float16* __restrict__ Wt,
    _Float16* __restrict__ x)
{
  const int tid  = threadIdx.x;
  const int w    = tid >> 6;
  const int lane = tid & 63;
  const int m16  = lane & 15;
  const int quad = lane >> 4;
  const int r = blockIdx.x * 64 + w * 16 + m16;     // row in [T*B], r = t*64 + b
  const int t = r >> 6;
  const int b = r & 63;
  const int erow = idx[b * T_SZ + t];
  const float* Arow = emb + (size_t)erow * E_SZ + quad * 8;   // A[m][k=quad*8+j]

  __shared__ __align__(16) _Float16 bp[2][16 * 64 * 8]; // 2 x 16KB fragment panels
  int n_[4], kb_[4];
#pragma unroll
  for (int pp = 0; pp < 4; ++pp) {
    int f = tid + 256 * pp;
    n_[pp]  = ((f >> 6) << 4) | (f & 15);
    kb_[pp] = (f >> 4) & 3;
  }
  uint4 stg[4];
#pragma unroll
  for (int pp = 0; pp < 4; ++pp)
    stg[pp] = *(const uint4*)(Wt + (size_t)n_[pp] * E_SZ + kb_[pp] * 8);
  f32x4 af0 = *(const f32x4*)(Arow);
  f32x4 af1 = *(const f32x4*)(Arow + 4);

  f32x4 acc[16];
#pragma unroll
  for (int n = 0; n < 16; ++n) { f32x4 z = {0.f, 0.f, 0.f, 0.f}; acc[n] = z; }

  // stage panel 0
#pragma unroll
  for (int pp = 0; pp < 4; ++pp)
    *(uint4*)(bp[0] + (size_t)(tid + 256 * pp) * 8) = stg[pp];
  __syncthreads();

#pragma unroll 1
  for (int ki = 0; ki < 24; ++ki) {
    const _Float16* cur = bp[ki & 1];
    f32x4 af0n = af0, af1n = af1;
    if (ki < 23) {                            // prefetch next panel + next A
#pragma unroll
      for (int pp = 0; pp < 4; ++pp)
        stg[pp] = *(const uint4*)(Wt + (size_t)n_[pp] * E_SZ + (ki + 1) * 32 + kb_[pp] * 8);
      af0n = *(const f32x4*)(Arow + (ki + 1) * 32);
      af1n = *(const f32x4*)(Arow + (ki + 1) * 32 + 4);
    }
    half8 a;
#pragma unroll
    for (int e = 0; e < 4; ++e) { a[e] = (_Float16)af0[e]; a[4 + e] = (_Float16)af1[e]; }
#pragma unroll
    for (int nt = 0; nt < 16; ++nt) {
      half8 bb = *(const half8*)(cur + (size_t)(nt * 64 + lane) * 8);
      acc[nt] = __builtin_amdgcn_mfma_f32_16x16x32_f16(a, bb, acc[nt], 0, 0, 0);
    }
    if (ki < 23) {                            // write next buffer, one barrier
#pragma unroll
      for (int pp = 0; pp < 4; ++pp)
        *(uint4*)(bp[(ki + 1) & 1] + (size_t)(tid + 256 * pp) * 8) = stg[pp];
      __syncthreads();
    }
    af0 = af0n; af1 = af1n;
  }
  const int rbase = blockIdx.x * 64 + w * 16 + quad * 4;  // C/D: col=lane&15, row=quad*4+reg
#pragma unroll
  for (int nt = 0; nt < 16; ++nt) {
    const int col = nt * 16 + m16;
#pragma unroll
    for (int rg = 0; rg < 4; ++rg) {
      x[(size_t)(rbase + rg) * H_SZ + col] = (_Float16)acc[nt][rg];
    }
  }
}

// ---------------- k2: 4-way K-split VALU-dot2 recurrence, VGPR-pinned ----------------
// R1-R3 post-mortem: allocator parks loop-invariant weight arrays in AGPRs
// (VGPR_Count=92/92/48 across wc[128]/wc[128]/wc[64]) and v_dot2 can't source
// AGPRs -> ~350 cyc/step of v_accvgpr_read copies (measured via VALUBusy
// reconciliation: 648 cyc issue vs ~296 algorithmic). Policy, not pressure.
// Fix: (a) empty asm "+v" pins inside the loop force wc into arch VGPRs every
// iteration (zero instructions, class constraint only); (b) 4-way K-split ->
// wc[32]/thread, 16 waves = 4 waves/SIMD to cover barrier/LDS-latency windows.
// Per-SIMD dot issue unchanged: 4 waves x 32 dots x 2cyc = 256 cyc = floor.
__global__ __launch_bounds__(1024, 4) void k2_rnn(
    const unsigned int* __restrict__ Wq,
    const _Float16* __restrict__ x,
    const float* __restrict__ Bh,
    float* __restrict__ hout,
    float* __restrict__ hidout)
{
  const int b   = blockIdx.x;
  const int tid = threadIdx.x;        // 0..1023
  const int g   = tid >> 8;           // K-quarter: rows [g*64, g*64+64)
  const int c   = tid & 255;          // output column
  __shared__ __align__(16) _Float16 hb[2][H_SZ];   // h as f16, double-buffered
  __shared__ float part[3][H_SZ];                  // g=1..3 partial sums

  // wc[i] = packed pair (Whh[2*(g*32+i)][c], Whh[2*(g*32+i)+1][c])
  unsigned int wc[32];
#pragma unroll
  for (int i = 0; i < 32; ++i)
    wc[i] = Wq[(size_t)(g * 32 + i) * H_SZ + c];

  const float bhj = Bh[c];
  const _Float16* xp = x + b * H_SZ + c;
  _Float16 xA = xp[0];                               // for t=0
  _Float16 xB = xp[(size_t)(B_SZ * H_SZ)];           // for t=1
  if (tid < H_SZ) hb[1][tid] = (_Float16)0.f;        // t=0 reads buffer 1 = zeros
  float hval = 0.f;
  __syncthreads();

#define DOT4(Q, KB) \
  a0 = dot2(Q.x, wc[4 * (KB) + 0], a0); \
  a1 = dot2(Q.y, wc[4 * (KB) + 1], a1); \
  a2 = dot2(Q.z, wc[4 * (KB) + 2], a2); \
  a3 = dot2(Q.w, wc[4 * (KB) + 3], a3);

#define K2_STEP(HR, HW, XREG)                                          \
  {                                                                    \
    const uint4* hq4 = ((const uint4*)(HR)) + g * 8;                   \
    uint4 q0 = hq4[0], q1 = hq4[1], q2 = hq4[2], q3 = hq4[3],          \
          q4 = hq4[4], q5 = hq4[5], q6 = hq4[6], q7 = hq4[7];          \
    float a0 = 0.f, a1 = 0.f, a2 = 0.f, a3 = 0.f;                      \
    DOT4(q0, 0) DOT4(q1, 1) DOT4(q2, 2) DOT4(q3, 3)                    \
    DOT4(q4, 4) DOT4(q5, 5) DOT4(q6, 6) DOT4(q7, 7)                    \
    float psum = (a0 + a1) + (a2 + a3);                                \
    if (g) part[g - 1][c] = psum;                                      \
    __syncthreads();                                                   \
    if (!g) {                                                          \
      float y = psum + part[0][c] + part[1][c] + part[2][c]            \
                + (float)(XREG) + bhj;                                 \
      hval = fast_tanh(y);                                             \
      (HW)[c] = (_Float16)hval;                                        \
    }                                                                  \
    __syncthreads();                                                   \
  }

#pragma unroll 1
  for (int tt = 0; tt < 256; ++tt) {
    // pin weight words to arch-VGPR class once per iteration (0 instructions)
    asm volatile("" : "+v"(wc[0]), "+v"(wc[1]), "+v"(wc[2]), "+v"(wc[3]),
                      "+v"(wc[4]), "+v"(wc[5]), "+v"(wc[6]), "+v"(wc[7]));
    asm volatile("" : "+v"(wc[8]), "+v"(wc[9]), "+v"(wc[10]), "+v"(wc[11]),
                      "+v"(wc[12]), "+v"(wc[13]), "+v"(wc[14]), "+v"(wc[15]));
    asm volatile("" : "+v"(wc[16]), "+v"(wc[17]), "+v"(wc[18]), "+v"(wc[19]),
                      "+v"(wc[20]), "+v"(wc[21]), "+v"(wc[22]), "+v"(wc[23]));
    asm volatile("" : "+v"(wc[24]), "+v"(wc[25]), "+v"(wc[26]), "+v"(wc[27]),
                      "+v"(wc[28]), "+v"(wc[29]), "+v"(wc[30]), "+v"(wc[31]));
    // ---- step A: t = 2tt, read hb[1], write hb[0]
    int ta = 2 * tt + 2; ta = ta > 511 ? 511 : ta;
    _Float16 xAc = xA;
    xA = xp[(size_t)ta * (B_SZ * H_SZ)];   // reload same reg: wait is 2 steps out
    K2_STEP(hb[1], hb[0], xAc)
    // ---- step B: t = 2tt+1, read hb[0], write hb[1]
    int tb = 2 * tt + 3; tb = tb > 511 ? 511 : tb;
    _Float16 xBc = xB;
    xB = xp[(size_t)tb * (B_SZ * H_SZ)];
    K2_STEP(hb[0], hb[1], xBc)
  }
#undef K2_STEP
#undef DOT4
  if (!g) {
    hout[b * H_SZ + c] = hval;
    hidout[b * H_SZ + c] = hval;
  }
}

// ---------------- k3: out = hidden @ Wy + By  (all f32) ----------------
__global__ __launch_bounds__(256) void k3_out(
    const float* __restrict__ h,
    const float* __restrict__ Wy,
    const float* __restrict__ By,
    float* __restrict__ out)
{
  __shared__ float hs[H_SZ];
  const int c = blockIdx.x;   // vocab chunk
  const int b = blockIdx.y;   // batch
  const int v = c * 256 + threadIdx.x;
  hs[threadIdx.x] = h[b * H_SZ + threadIdx.x];
  __syncthreads();
  float acc = By[v];
#pragma unroll 8
  for (int jj = 0; jj < H_SZ; ++jj) {
    acc += hs[jj] * Wy[(size_t)jj * V_SZ + v];
  }
  out[(size_t)b * V_SZ + v] = acc;
}

extern "C" void kernel_launch(void* const* d_in, const int* in_sizes, int n_in,
                              void* d_out, int out_size, void* d_ws, size_t ws_size,
                              hipStream_t stream)
{
  const int*   idx = (const int*)d_in[0];
  const float* emb = (const float*)d_in[1];
  const float* Wxh = (const float*)d_in[2];
  const float* Whh = (const float*)d_in[3];
  const float* Wy  = (const float*)d_in[4];
  const float* By  = (const float*)d_in[5];
  const float* Bh  = (const float*)d_in[6];

  char* ws = (char*)d_ws;
  _Float16*     x    = (_Float16*)(ws + WS_X);
  _Float16*     Wt   = (_Float16*)(ws + WS_WT);
  unsigned int* Wq   = (unsigned int*)(ws + WS_WQ);
  float*        hbuf = (float*)(ws + WS_H);

  float* out    = (float*)d_out;
  float* hidout = out + (size_t)B_SZ * V_SZ;

  k0_convert<<<768, 256, 0, stream>>>(Wxh, Whh, Wt, Wq);
  k1_xproj  <<<512, 256, 0, stream>>>(idx, emb, Wt, x);
  k2_rnn    <<<64, 1024, 0, stream>>>(Wq, x, Bh, hbuf, hidout);
  k3_out    <<<dim3(12, 64), 256, 0, stream>>>(hbuf, Wy, By, out);
}